// Round 7
// baseline (617.927 us; speedup 1.0000x reference)
//
#include <hip/hip_runtime.h>
#include <hip/hip_bf16.h>

// ---------------- problem constants (fixed by reference) ----------------
#define NN 20000
#define EE 200000
#define FIN 512
#define HID 1024
#define OUTF 128
#define MPAD 20224   // 79*256 (and 158*128): GEMM A-tiles never read past buffer end

typedef unsigned short ush;
typedef __attribute__((ext_vector_type(8))) short bf16x8;  // 8 bf16 (4 VGPR)
typedef __attribute__((ext_vector_type(4))) float f32x4;   // MFMA accumulator

// ---------------- bf16 split helpers ----------------
__device__ __forceinline__ ush f2bf_rne(float f) {
    union { float f; unsigned u; } a; a.f = f;
    unsigned u = a.u;
    return (ush)((u + 0x7fffu + ((u >> 16) & 1u)) >> 16);
}
__device__ __forceinline__ float bf2f(ush h) {
    union { float f; unsigned u; } a; a.u = ((unsigned)h) << 16;
    return a.f;
}
__device__ __forceinline__ void split_bf(float v, ush& hi, ush& lo) {
    hi = f2bf_rne(v);
    lo = f2bf_rne(v - bf2f(hi));   // v - hi is exact in fp32
}

// async global->LDS, 16B per lane (literal size per guide)
__device__ __forceinline__ void gl16(const void* g, void* l) {
    __builtin_amdgcn_global_load_lds(
        (const __attribute__((address_space(1))) unsigned*)g,
        (__attribute__((address_space(3))) unsigned*)l, 16, 0, 0);
}

// ---------------- graph preprocessing ----------------
__global__ void init_kernel(float* deg, int* cnt, int n) {
    int i = blockIdx.x * blockDim.x + threadIdx.x;
    if (i < n) { deg[i] = 1.0f; cnt[i] = 0; }   // self-loop weight 1
}

__global__ void deg_count_kernel(const int* __restrict__ ei, const float* __restrict__ ew,
                                 float* deg, int* cnt, int e) {
    int idx = blockIdx.x * blockDim.x + threadIdx.x;
    if (idx < e) {
        int c = ei[EE + idx];
        atomicAdd(&deg[c], ew[idx]);
        atomicAdd(&cnt[c], 1);
    }
}

__global__ void dis_kernel(const float* __restrict__ deg, float* dis, int n) {
    int i = blockIdx.x * blockDim.x + threadIdx.x;
    if (i < n) dis[i] = rsqrtf(deg[i]);
}

// bias1s = b1 + rb1 (HID); bias2c[256]: [0..127]=0, [128..255]=b2+rb2
__global__ void bias_kernel(const float* __restrict__ b1, const float* __restrict__ rb1,
                            const float* __restrict__ b2, const float* __restrict__ rb2,
                            float* bias1s, float* bias2c) {
    int i = blockIdx.x * blockDim.x + threadIdx.x;
    if (i < HID) bias1s[i] = b1[i] + rb1[i];
    if (i < 256) bias2c[i] = (i < 128) ? 0.0f : (b2[i - 128] + rb2[i - 128]);
}

#define SCAN_THREADS 1024
#define SCAN_CHUNK 20
__global__ __launch_bounds__(SCAN_THREADS)
void scan_kernel(const int* __restrict__ cnt, int* rowptr, int* cursor, int n, int total_e) {
    __shared__ int part[SCAN_THREADS];
    int t = threadIdx.x;
    int base = t * SCAN_CHUNK;
    int s = 0;
    for (int j = 0; j < SCAN_CHUNK; ++j) { int i = base + j; if (i < n) s += cnt[i]; }
    part[t] = s;
    __syncthreads();
    for (int off = 1; off < SCAN_THREADS; off <<= 1) {
        int add = (t >= off) ? part[t - off] : 0;
        __syncthreads();
        part[t] += add;
        __syncthreads();
    }
    int run = (t == 0) ? 0 : part[t - 1];
    for (int j = 0; j < SCAN_CHUNK; ++j) {
        int i = base + j;
        if (i < n) { rowptr[i] = run; cursor[i] = run; run += cnt[i]; }
    }
    if (t == SCAN_THREADS - 1) rowptr[n] = total_e;
}

__global__ void scatter_kernel(const int* __restrict__ ei, const float* __restrict__ ew,
                               const float* __restrict__ dis, int* cursor,
                               int* srcs, float* norms, int e) {
    int idx = blockIdx.x * blockDim.x + threadIdx.x;
    if (idx < e) {
        int r = ei[idx];
        int c = ei[EE + idx];
        float nv = dis[r] * ew[idx] * dis[c];
        int p = atomicAdd(&cursor[c], 1);
        srcs[p] = r;
        norms[p] = nv;
    }
}

// ---------------- transpose + split weights: src[K][N] f32 -> dst[N][ldst] bf16 hi/lo ----------------
__global__ __launch_bounds__(256)
void tsplit_kernel(const float* __restrict__ src, int K, int N,
                   ush* __restrict__ dh, ush* __restrict__ dl, int ldst, int koff) {
    __shared__ float tile[32][33];
    int tx = threadIdx.x & 31, ty = threadIdx.x >> 5;   // 32 x 8
    int n0 = blockIdx.x * 32, k0 = blockIdx.y * 32;
#pragma unroll
    for (int i = 0; i < 4; ++i)
        tile[ty * 4 + i][tx] = src[(size_t)(k0 + ty * 4 + i) * N + n0 + tx];
    __syncthreads();
#pragma unroll
    for (int i = 0; i < 4; ++i) {
        int n = n0 + ty * 4 + i, k = k0 + tx;
        float v = tile[tx][ty * 4 + i];
        ush h, lo; split_bf(v, h, lo);
        size_t off = (size_t)n * ldst + koff + k;
        dh[off] = h;
        dl[off] = lo;
    }
}

// ---------------- pre-aggregation of x -> ax hi/lo planes; also splits x itself ----------------
__global__ __launch_bounds__(128)
void aggx_kernel(const float* __restrict__ x,
                 ush* __restrict__ xh, ush* __restrict__ xl,
                 ush* __restrict__ axh, ush* __restrict__ axl,
                 const float* __restrict__ dis,
                 const int* __restrict__ rowptr, const int* __restrict__ srcs,
                 const float* __restrict__ norms) {
    int i = blockIdx.x;
    int t = threadIdx.x;
    float d = dis[i];
    float d2 = d * d;
    float4 v = ((const float4*)(x + (size_t)i * FIN))[t];

    ushort4 vh, vl;
    split_bf(v.x, vh.x, vl.x); split_bf(v.y, vh.y, vl.y);
    split_bf(v.z, vh.z, vl.z); split_bf(v.w, vh.w, vl.w);
    ((ushort4*)(xh + (size_t)i * FIN))[t] = vh;
    ((ushort4*)(xl + (size_t)i * FIN))[t] = vl;

    float s0 = d2 * v.x, s1 = d2 * v.y, s2 = d2 * v.z, s3 = d2 * v.w;
    int beg = rowptr[i], end = rowptr[i + 1];
    int j = beg;
    for (; j + 2 <= end; j += 2) {
        int sa = srcs[j], sb = srcs[j + 1];
        float wa = norms[j], wb = norms[j + 1];
        float4 ua = ((const float4*)(x + (size_t)sa * FIN))[t];
        float4 ub = ((const float4*)(x + (size_t)sb * FIN))[t];
        s0 += wa * ua.x + wb * ub.x;
        s1 += wa * ua.y + wb * ub.y;
        s2 += wa * ua.z + wb * ub.z;
        s3 += wa * ua.w + wb * ub.w;
    }
    if (j < end) {
        int sa = srcs[j];
        float wa = norms[j];
        float4 ua = ((const float4*)(x + (size_t)sa * FIN))[t];
        s0 += wa * ua.x; s1 += wa * ua.y; s2 += wa * ua.z; s3 += wa * ua.w;
    }
    ushort4 hv, lv;
    split_bf(s0, hv.x, lv.x); split_bf(s1, hv.y, lv.y);
    split_bf(s2, hv.z, lv.z); split_bf(s3, hv.w, lv.w);
    ((ushort4*)(axh + (size_t)i * FIN))[t] = hv;
    ((ushort4*)(axl + (size_t)i * FIN))[t] = lv;
}

// ---------------- layer-1 GEMM: 256^2 tile, virtual-K=3072, counted-vmcnt pipeline ----------------
// h = relu([ax|x] @ [w1;rw1] + bias), split-bf16 as 3 K-segments:
//   seg0: Ahi*Bhi, seg1: Ahi*Blo, seg2: Alo*Bhi  (virtual K = 3*1024, BK=32 -> 96 tiles)
// 512 threads = 8 waves (2 Mrow x 4 Ncol), per-wave out 128x64, acc 8x4 f32x4.
// LDS: 4-slot ring (A,B each 4x16KiB = 128 KiB); prefetch 3 tiles ahead via global_load_lds.
// Per tile: ONE raw s_barrier + ONE s_waitcnt vmcnt(8) (counted, never 0 -> loads stay in
// flight across barriers; this removes the __syncthreads vmcnt(0) drain = the m97 stall).
// T2 XOR swizzle (chunk ^= (row>>1)&3) applied on BOTH stage-source and ds_read (involution).
// Tail staging is CLAMPED (re-stages tile 95) so vmcnt accounting stays invariant.
__global__ __launch_bounds__(512, 2)
void gemm256(const ush* __restrict__ axh, const ush* __restrict__ axl,
             const ush* __restrict__ xh,  const ush* __restrict__ xl,
             const ush* __restrict__ bth, const ush* __restrict__ btl,
             const float* __restrict__ bias,
             ush* __restrict__ Chh, ush* __restrict__ Chl) {
    __shared__ ush LA[4 * 8192];   // 4 slots x 256 rows x 32 bf16
    __shared__ ush LB[4 * 8192];

    // bijective XCD swizzle (m204), nwg = 4*79 = 316
    int nwg = gridDim.x * gridDim.y;
    int orig = blockIdx.y * gridDim.x + blockIdx.x;
    int xcd = orig & 7, slot0 = orig >> 3;
    int q = nwg >> 3, r = nwg & 7;
    int wg = (xcd < r ? xcd * (q + 1) : r * (q + 1) + (xcd - r) * q) + slot0;
    int bn = (wg & 3) * 256;         // gridDim.x == 4, n fastest
    int bm = (wg >> 2) * 256;

    int t = threadIdx.x;
    int l = t & 63, w = t >> 6;
    int wr = w >> 2, wc = w & 3;     // 2 x 4 waves

    // staging: 2 x 16B chunks per operand per tile per thread (1024 chunks / 512 thr)
    int cidx0 = t, cidx1 = t + 512;
    int srow0 = cidx0 >> 2, srow1 = cidx1 >> 2;
    int sc0 = (cidx0 & 3) ^ ((cidx0 >> 3) & 3);   // swizzled source chunk
    int sc1 = (cidx1 & 3) ^ ((cidx1 >> 3) & 3);
    int ld0 = cidx0 * 16, ld1 = cidx1 * 16;       // linear LDS byte dests

    // ds_read addressing: kslot XOR'd with (row>>1)&3 == (l>>1)&3 for 16-aligned frag rows
    int ksw16 = (((l >> 4) ^ ((l >> 1) & 3)) << 4);
    int arow = wr * 128 + (l & 15);
    int bcol = wc * 64 + (l & 15);

    f32x4 acc[8][4];
#pragma unroll
    for (int i = 0; i < 8; ++i)
#pragma unroll
        for (int j = 0; j < 4; ++j) acc[i][j] = (f32x4){0.f, 0.f, 0.f, 0.f};

    auto stage = [&](int kt, int s) {
        int seg = kt >> 5;                 // 0,1,2
        int kk = (kt & 31) << 5;           // 0..992 within segment
        const ush* Ap = (seg < 2) ? ((kk < FIN) ? axh : xh)
                                  : ((kk < FIN) ? axl : xl);
        int ka = kk & (FIN - 1);
        const ush* Bp = (seg == 1) ? btl : bth;
        char* la = (char*)LA + s * 16384;
        char* lb = (char*)LB + s * 16384;
        gl16(Ap + (size_t)(bm + srow0) * FIN + ka + sc0 * 8, la + ld0);
        gl16(Ap + (size_t)(bm + srow1) * FIN + ka + sc1 * 8, la + ld1);
        gl16(Bp + (size_t)(bn + srow0) * HID + kk + sc0 * 8, lb + ld0);
        gl16(Bp + (size_t)(bn + srow1) * HID + kk + sc1 * 8, lb + ld1);
    };

    // prologue: 3 tiles in flight; vmcnt(8) completes tile 0's 4 loads
    stage(0, 0); stage(1, 1); stage(2, 2);
    asm volatile("s_waitcnt vmcnt(8)" ::: "memory");
    __builtin_amdgcn_s_barrier();
    __builtin_amdgcn_sched_barrier(0);

    for (int kt = 0; kt < 96; ++kt) {
        int s = kt & 3;
        const char* la = (const char*)LA + s * 16384;
        const char* lb = (const char*)LB + s * 16384;
        bf16x8 a[8], b[4];
#pragma unroll
        for (int fm = 0; fm < 8; ++fm)
            a[fm] = *(const bf16x8*)(la + (arow + fm * 16) * 64 + ksw16);
#pragma unroll
        for (int fn = 0; fn < 4; ++fn)
            b[fn] = *(const bf16x8*)(lb + (bcol + fn * 16) * 64 + ksw16);

        int nx = kt + 3; if (nx > 95) nx = 95;   // clamp keeps vmcnt counts invariant
        stage(nx, (kt + 3) & 3);

        __builtin_amdgcn_s_setprio(1);
#pragma unroll
        for (int fm = 0; fm < 8; ++fm)
#pragma unroll
            for (int fn = 0; fn < 4; ++fn)
                acc[fm][fn] = __builtin_amdgcn_mfma_f32_16x16x32_bf16(a[fm], b[fn], acc[fm][fn], 0, 0, 0);
        __builtin_amdgcn_s_setprio(0);

        __builtin_amdgcn_sched_barrier(0);                 // pin: MFMAs before the wait
        asm volatile("s_waitcnt vmcnt(8)" ::: "memory");   // oldest 4 = tile kt+1 complete
        __builtin_amdgcn_s_barrier();                      // raw: no vmcnt(0) drain
        __builtin_amdgcn_sched_barrier(0);                 // pin: next reads after barrier
    }

    // epilogue: C/D 16x16 mapping (verified): col = lane&15, row = (lane>>4)*4 + reg
    int ccol = bn + wc * 64 + (l & 15);
    float bb[4];
#pragma unroll
    for (int fn = 0; fn < 4; ++fn) bb[fn] = bias[ccol + fn * 16];
#pragma unroll
    for (int fm = 0; fm < 8; ++fm)
#pragma unroll
        for (int j = 0; j < 4; ++j) {
            int row = bm + wr * 128 + fm * 16 + ((l >> 4) << 2) + j;
            if (row < NN) {
#pragma unroll
                for (int fn = 0; fn < 4; ++fn) {
                    float v = fmaxf(acc[fm][fn][j] + bb[fn], 0.0f);
                    ush hi, lo; split_bf(v, hi, lo);
                    size_t off = (size_t)row * HID + ccol + fn * 16;
                    Chh[off] = hi;
                    Chl[off] = lo;
                }
            }
        }
}

// ---------------- layer-2 MFMA split-bf16 GEMM (128^2, dbuf 2-phase + XCD swizzle) ----------------
__global__ __launch_bounds__(256)
void gemm_mfma(const ush* __restrict__ A0h, const ush* __restrict__ A0l,
               const ush* __restrict__ A1h, const ush* __restrict__ A1l,
               int ksw, int KA,
               const ush* __restrict__ BTh, const ush* __restrict__ BTl,
               const float* __restrict__ bias,
               float* __restrict__ Cf, ush* __restrict__ Chh, ush* __restrict__ Chl,
               int M, int N, int K, int mode) {
    __shared__ ush Ah[2][128 * 32], Al[2][128 * 32], Bh[2][128 * 32], Bl[2][128 * 32];

    int nwg = gridDim.x * gridDim.y;
    int orig = blockIdx.y * gridDim.x + blockIdx.x;
    int xcd = orig & 7, slot = orig >> 3;
    int q = nwg >> 3, r = nwg & 7;
    int wg = (xcd < r ? xcd * (q + 1) : r * (q + 1) + (xcd - r) * q) + slot;
    int bn = (wg % gridDim.x) * 128;
    int bm = (wg / gridDim.x) * 128;

    int t = threadIdx.x;
    int l = t & 63, w = t >> 6;
    int wr = w >> 1, wc = w & 1;

    int sr = t >> 2;
    int sg8 = (t & 3) * 8;
    size_t a_off0 = (size_t)(bm + sr) * KA + sg8;
    size_t a_off1 = (size_t)(bm + 64 + sr) * KA + sg8;
    size_t b_off0 = (size_t)(bn + sr) * K + sg8;
    size_t b_off1 = (size_t)(bn + 64 + sr) * K + sg8;
    int lo0 = t * 16, lo1 = t * 16 + 4096;

    int abase = (wr * 64 + (l & 15)) * 64 + ((l >> 4) << 4);
    int bbase = (wc * 64 + (l & 15)) * 64 + ((l >> 4) << 4);

    auto stage = [&](int kt, int b) {
        const ush* Asrch; const ush* Asrcl; int kk;
        if (kt < ksw) { Asrch = A0h; Asrcl = A0l; kk = kt; }
        else          { Asrch = A1h; Asrcl = A1l; kk = kt - ksw; }
        gl16(Asrch + a_off0 + kk, (char*)Ah[b] + lo0);
        gl16(Asrch + a_off1 + kk, (char*)Ah[b] + lo1);
        gl16(Asrcl + a_off0 + kk, (char*)Al[b] + lo0);
        gl16(Asrcl + a_off1 + kk, (char*)Al[b] + lo1);
        gl16(BTh + b_off0 + kt, (char*)Bh[b] + lo0);
        gl16(BTh + b_off1 + kt, (char*)Bh[b] + lo1);
        gl16(BTl + b_off0 + kt, (char*)Bl[b] + lo0);
        gl16(BTl + b_off1 + kt, (char*)Bl[b] + lo1);
    };

    f32x4 acc[4][4];
#pragma unroll
    for (int i = 0; i < 4; ++i)
#pragma unroll
        for (int j = 0; j < 4; ++j) acc[i][j] = (f32x4){0.f, 0.f, 0.f, 0.f};

    stage(0, 0);
    __syncthreads();

    int cur = 0;
    for (int kt = 0; kt < K; kt += 32) {
        if (kt + 32 < K) stage(kt + 32, cur ^ 1);

        bf16x8 ah[4], al[4], bh[4], bl[4];
#pragma unroll
        for (int f = 0; f < 4; ++f) {
            ah[f] = *(const bf16x8*)((const char*)Ah[cur] + abase + f * 1024);
            al[f] = *(const bf16x8*)((const char*)Al[cur] + abase + f * 1024);
            bh[f] = *(const bf16x8*)((const char*)Bh[cur] + bbase + f * 1024);
            bl[f] = *(const bf16x8*)((const char*)Bl[cur] + bbase + f * 1024);
        }
#pragma unroll
        for (int fm = 0; fm < 4; ++fm)
#pragma unroll
            for (int fn = 0; fn < 4; ++fn)
                acc[fm][fn] = __builtin_amdgcn_mfma_f32_16x16x32_bf16(ah[fm], bh[fn], acc[fm][fn], 0, 0, 0);
#pragma unroll
        for (int fm = 0; fm < 4; ++fm)
#pragma unroll
            for (int fn = 0; fn < 4; ++fn)
                acc[fm][fn] = __builtin_amdgcn_mfma_f32_16x16x32_bf16(ah[fm], bl[fn], acc[fm][fn], 0, 0, 0);
#pragma unroll
        for (int fm = 0; fm < 4; ++fm)
#pragma unroll
            for (int fn = 0; fn < 4; ++fn)
                acc[fm][fn] = __builtin_amdgcn_mfma_f32_16x16x32_bf16(al[fm], bh[fn], acc[fm][fn], 0, 0, 0);

        __syncthreads();
        cur ^= 1;
    }

    int ccol = bn + wc * 64 + (l & 15);
    float bb[4];
#pragma unroll
    for (int fn = 0; fn < 4; ++fn) bb[fn] = bias ? bias[ccol + fn * 16] : 0.0f;

    if (mode) {
#pragma unroll
        for (int fm = 0; fm < 4; ++fm)
#pragma unroll
            for (int j = 0; j < 4; ++j) {
                int row = bm + wr * 64 + fm * 16 + ((l >> 4) << 2) + j;
                if (row < M) {
#pragma unroll
                    for (int fn = 0; fn < 4; ++fn) {
                        float v = fmaxf(acc[fm][fn][j] + bb[fn], 0.0f);
                        ush hi, lo; split_bf(v, hi, lo);
                        size_t off = (size_t)row * N + ccol + fn * 16;
                        Chh[off] = hi;
                        Chl[off] = lo;
                    }
                }
            }
    } else {
#pragma unroll
        for (int fm = 0; fm < 4; ++fm)
#pragma unroll
            for (int j = 0; j < 4; ++j) {
                int row = bm + wr * 64 + fm * 16 + ((l >> 4) << 2) + j;
                if (row < M) {
#pragma unroll
                    for (int fn = 0; fn < 4; ++fn)
                        Cf[(size_t)row * N + ccol + fn * 16] = acc[fm][fn][j] + bb[fn];
                }
            }
    }
}

// ---------------- layer-2 aggregation + residual -> out ----------------
__global__ __launch_bounds__(256)
void agg2_kernel(const float* __restrict__ z2, const float* __restrict__ dis,
                 const int* __restrict__ rowptr, const int* __restrict__ srcs,
                 const float* __restrict__ norms, float* __restrict__ out) {
    int wave = threadIdx.x >> 6;
    int lane = threadIdx.x & 63;
    int i = blockIdx.x * 4 + wave;
    float d = dis[i];
    float d2 = d * d;
    float2 v = ((const float2*)(z2 + (size_t)i * 256))[lane];
    float ax = d2 * v.x, ay = d2 * v.y;
    int beg = rowptr[i], end = rowptr[i + 1];
    int j = beg;
    for (; j + 2 <= end; j += 2) {
        int sa = srcs[j], sb = srcs[j + 1];
        float wa = norms[j], wb = norms[j + 1];
        float2 ua = ((const float2*)(z2 + (size_t)sa * 256))[lane];
        float2 ub = ((const float2*)(z2 + (size_t)sb * 256))[lane];
        ax += wa * ua.x + wb * ub.x;
        ay += wa * ua.y + wb * ub.y;
    }
    if (j < end) {
        int sa = srcs[j];
        float wa = norms[j];
        float2 ua = ((const float2*)(z2 + (size_t)sa * 256))[lane];
        ax += wa * ua.x; ay += wa * ua.y;
    }
    float2 rr = ((const float2*)(z2 + (size_t)i * 256 + 128))[lane];
    float2 o; o.x = ax + rr.x; o.y = ay + rr.y;
    ((float2*)(out + (size_t)i * OUTF))[lane] = o;
}

// ---------------- launch ----------------
extern "C" void kernel_launch(void* const* d_in, const int* in_sizes, int n_in,
                              void* d_out, int out_size, void* d_ws, size_t ws_size,
                              hipStream_t stream) {
    const float* x   = (const float*)d_in[0];
    const float* w1  = (const float*)d_in[1];
    const float* b1  = (const float*)d_in[2];
    const float* w2  = (const float*)d_in[3];
    const float* b2  = (const float*)d_in[4];
    const float* rw1 = (const float*)d_in[5];
    const float* rb1 = (const float*)d_in[6];
    const float* rw2 = (const float*)d_in[7];
    const float* rb2 = (const float*)d_in[8];
    const float* ew  = (const float*)d_in[9];
    const int*   ei  = (const int*)d_in[10];
    float* out = (float*)d_out;

    // -------- workspace layout (bytes) --------
    char* p = (char*)d_ws;
    ush* xh  = (ush*)p; p += (size_t)MPAD * FIN * 2;
    ush* xl  = (ush*)p; p += (size_t)MPAD * FIN * 2;
    ush* axh = (ush*)p; p += (size_t)MPAD * FIN * 2;
    ush* axl = (ush*)p; p += (size_t)MPAD * FIN * 2;
    ush* hh  = (ush*)p; p += (size_t)MPAD * HID * 2;
    ush* hl  = (ush*)p; p += (size_t)MPAD * HID * 2;
    ush* w1cth = (ush*)p; p += (size_t)HID * HID * 2;   // [1024 n][1024 k] = [w1;rw1]^T hi
    ush* w1ctl = (ush*)p; p += (size_t)HID * HID * 2;
    ush* w2cth = (ush*)p; p += (size_t)256 * HID * 2;   // [256 n][1024 k]: 0-127=w2^T, 128-255=rw2^T
    ush* w2ctl = (ush*)p; p += (size_t)256 * HID * 2;
    float* deg    = (float*)p; p += NN * 4;
    float* dis    = (float*)p; p += NN * 4;
    float* norms  = (float*)p; p += EE * 4;
    float* bias1s = (float*)p; p += HID * 4;
    float* bias2c = (float*)p; p += 256 * 4;
    int* rowptr = (int*)p; p += (NN + 1) * 4;
    int* cursor = (int*)p; p += NN * 4;
    int* cnt    = (int*)p; p += NN * 4;
    int* srcs   = (int*)p; p += EE * 4;
    float* z2 = (float*)xh;   // NN*256 f32 = 20.48 MB <= 20.7 MB plane (dead after layer-1)

    // 1. graph preprocessing
    init_kernel<<<(NN + 255) / 256, 256, 0, stream>>>(deg, cnt, NN);
    deg_count_kernel<<<(EE + 255) / 256, 256, 0, stream>>>(ei, ew, deg, cnt, EE);
    dis_kernel<<<(NN + 255) / 256, 256, 0, stream>>>(deg, dis, NN);
    bias_kernel<<<(HID + 255) / 256, 256, 0, stream>>>(b1, rb1, b2, rb2, bias1s, bias2c);
    scan_kernel<<<1, SCAN_THREADS, 0, stream>>>(cnt, rowptr, cursor, NN, EE);
    scatter_kernel<<<(EE + 255) / 256, 256, 0, stream>>>(ei, ew, dis, cursor, srcs, norms, EE);

    // 2. weight conversions
    { dim3 g(HID / 32, FIN / 32); tsplit_kernel<<<g, 256, 0, stream>>>(w1,  FIN, HID, w1cth, w1ctl, HID, 0);   }
    { dim3 g(HID / 32, FIN / 32); tsplit_kernel<<<g, 256, 0, stream>>>(rw1, FIN, HID, w1cth, w1ctl, HID, FIN); }
    { dim3 g(OUTF / 32, HID / 32); tsplit_kernel<<<g, 256, 0, stream>>>(w2,  HID, OUTF, w2cth, w2ctl, HID, 0); }
    { dim3 g(OUTF / 32, HID / 32); tsplit_kernel<<<g, 256, 0, stream>>>(rw2, HID, OUTF,
                                        w2cth + (size_t)128 * HID, w2ctl + (size_t)128 * HID, HID, 0); }

    // 3. pre-aggregate x -> ax planes (+ fused split of x)
    aggx_kernel<<<NN, 128, 0, stream>>>(x, xh, xl, axh, axl, dis, rowptr, srcs, norms);

    // 4. layer-1: 256^2 counted-vmcnt pipeline kernel
    {
        dim3 grid(HID / 256, MPAD / 256);   // 4 x 79
        gemm256<<<grid, 512, 0, stream>>>(axh, axl, xh, xl, w1cth, w1ctl, bias1s, hh, hl);
    }
    // 5. layer-2 combined GEMM: z2 = h @ [w2|rw2] + [0|b2+rb2]   (N=256)
    {
        dim3 grid(256 / 128, MPAD / 128);   // 2 x 158
        gemm_mfma<<<grid, 256, 0, stream>>>(hh, hl, hh, hl, HID, HID,
                                            w2cth, w2ctl, bias2c,
                                            z2, nullptr, nullptr,
                                            NN, 256, HID, 0);
    }
    // 6. layer-2 aggregation + residual -> out
    agg2_kernel<<<NN / 4, 256, 0, stream>>>(z2, dis, rowptr, srcs, norms, out);
}

// Round 9
// 463.228 us; speedup vs baseline: 1.3340x; 1.3340x over previous
//
#include <hip/hip_runtime.h>
#include <hip/hip_bf16.h>

// ---------------- problem constants (fixed by reference) ----------------
#define NN 20000
#define EE 200000
#define FIN 512
#define HID 1024
#define OUTF 128
#define MPAD 20224   // 158*128: GEMM A-tiles never read past buffer end

typedef unsigned short ush;
typedef __attribute__((ext_vector_type(8))) short bf16x8;  // 8 bf16 (4 VGPR)
typedef __attribute__((ext_vector_type(4))) float f32x4;   // MFMA accumulator

// ---------------- bf16 split helpers ----------------
__device__ __forceinline__ ush f2bf_rne(float f) {
    union { float f; unsigned u; } a; a.f = f;
    unsigned u = a.u;
    return (ush)((u + 0x7fffu + ((u >> 16) & 1u)) >> 16);
}
__device__ __forceinline__ float bf2f(ush h) {
    union { float f; unsigned u; } a; a.u = ((unsigned)h) << 16;
    return a.f;
}
__device__ __forceinline__ void split_bf(float v, ush& hi, ush& lo) {
    hi = f2bf_rne(v);
    lo = f2bf_rne(v - bf2f(hi));   // v - hi is exact in fp32
}

// async global->LDS, 16B per lane (literal size per guide)
__device__ __forceinline__ void gl16(const void* g, void* l) {
    __builtin_amdgcn_global_load_lds(
        (const __attribute__((address_space(1))) unsigned*)g,
        (__attribute__((address_space(3))) unsigned*)l, 16, 0, 0);
}

// ---------------- graph preprocessing ----------------
// init deg/cnt + fused bias prep: bias1s = b1+rb1; bias2c[256]: [0..127]=0, [128..255]=b2+rb2
__global__ void init_kernel(float* deg, int* cnt, int n,
                            const float* __restrict__ b1, const float* __restrict__ rb1,
                            const float* __restrict__ b2, const float* __restrict__ rb2,
                            float* bias1s, float* bias2c) {
    int i = blockIdx.x * blockDim.x + threadIdx.x;
    if (i < n) { deg[i] = 1.0f; cnt[i] = 0; }   // self-loop weight 1
    if (i < HID) bias1s[i] = b1[i] + rb1[i];
    if (i < 256) bias2c[i] = (i < 128) ? 0.0f : (b2[i - 128] + rb2[i - 128]);
}

__global__ void deg_count_kernel(const int* __restrict__ ei, const float* __restrict__ ew,
                                 float* deg, int* cnt, int e) {
    int idx = blockIdx.x * blockDim.x + threadIdx.x;
    if (idx < e) {
        int c = ei[EE + idx];
        atomicAdd(&deg[c], ew[idx]);
        atomicAdd(&cnt[c], 1);
    }
}

#define SCAN_THREADS 1024
#define SCAN_CHUNK 20
// prefix-scan of cnt -> rowptr/cursor; also computes dis = rsqrt(deg) (fused)
__global__ __launch_bounds__(SCAN_THREADS)
void scan_kernel(const int* __restrict__ cnt, int* rowptr, int* cursor, int n, int total_e,
                 const float* __restrict__ deg, float* __restrict__ dis) {
    __shared__ int part[SCAN_THREADS];
    int t = threadIdx.x;
    int base = t * SCAN_CHUNK;
    int s = 0;
    for (int j = 0; j < SCAN_CHUNK; ++j) {
        int i = base + j;
        if (i < n) { s += cnt[i]; dis[i] = rsqrtf(deg[i]); }
    }
    part[t] = s;
    __syncthreads();
    for (int off = 1; off < SCAN_THREADS; off <<= 1) {
        int add = (t >= off) ? part[t - off] : 0;
        __syncthreads();
        part[t] += add;
        __syncthreads();
    }
    int run = (t == 0) ? 0 : part[t - 1];
    for (int j = 0; j < SCAN_CHUNK; ++j) {
        int i = base + j;
        if (i < n) { rowptr[i] = run; cursor[i] = run; run += cnt[i]; }
    }
    if (t == SCAN_THREADS - 1) rowptr[n] = total_e;
}

__global__ void scatter_kernel(const int* __restrict__ ei, const float* __restrict__ ew,
                               const float* __restrict__ dis, int* cursor,
                               int* srcs, float* norms, int e) {
    int idx = blockIdx.x * blockDim.x + threadIdx.x;
    if (idx < e) {
        int r = ei[idx];
        int c = ei[EE + idx];
        float nv = dis[r] * ew[idx] * dis[c];
        int p = atomicAdd(&cursor[c], 1);
        srcs[p] = r;
        norms[p] = nv;
    }
}

// ---------------- transpose + split weights: src[K][N] f32 -> dst[N][ldst] bf16 hi/lo ----------------
__global__ __launch_bounds__(256)
void tsplit_kernel(const float* __restrict__ src, int K, int N,
                   ush* __restrict__ dh, ush* __restrict__ dl, int ldst, int koff) {
    __shared__ float tile[32][33];
    int tx = threadIdx.x & 31, ty = threadIdx.x >> 5;   // 32 x 8
    int n0 = blockIdx.x * 32, k0 = blockIdx.y * 32;
#pragma unroll
    for (int i = 0; i < 4; ++i)
        tile[ty * 4 + i][tx] = src[(size_t)(k0 + ty * 4 + i) * N + n0 + tx];
    __syncthreads();
#pragma unroll
    for (int i = 0; i < 4; ++i) {
        int n = n0 + ty * 4 + i, k = k0 + tx;
        float v = tile[tx][ty * 4 + i];
        ush h, lo; split_bf(v, h, lo);
        size_t off = (size_t)n * ldst + koff + k;
        dh[off] = h;
        dl[off] = lo;
    }
}

// ---------------- pre-aggregation of x -> ax hi/lo planes; also splits x itself ----------------
__global__ __launch_bounds__(128)
void aggx_kernel(const float* __restrict__ x,
                 ush* __restrict__ xh, ush* __restrict__ xl,
                 ush* __restrict__ axh, ush* __restrict__ axl,
                 const float* __restrict__ dis,
                 const int* __restrict__ rowptr, const int* __restrict__ srcs,
                 const float* __restrict__ norms) {
    int i = blockIdx.x;
    int t = threadIdx.x;
    float d = dis[i];
    float d2 = d * d;
    float4 v = ((const float4*)(x + (size_t)i * FIN))[t];

    ushort4 vh, vl;
    split_bf(v.x, vh.x, vl.x); split_bf(v.y, vh.y, vl.y);
    split_bf(v.z, vh.z, vl.z); split_bf(v.w, vh.w, vl.w);
    ((ushort4*)(xh + (size_t)i * FIN))[t] = vh;
    ((ushort4*)(xl + (size_t)i * FIN))[t] = vl;

    float s0 = d2 * v.x, s1 = d2 * v.y, s2 = d2 * v.z, s3 = d2 * v.w;
    int beg = rowptr[i], end = rowptr[i + 1];
    int j = beg;
    for (; j + 2 <= end; j += 2) {
        int sa = srcs[j], sb = srcs[j + 1];
        float wa = norms[j], wb = norms[j + 1];
        float4 ua = ((const float4*)(x + (size_t)sa * FIN))[t];
        float4 ub = ((const float4*)(x + (size_t)sb * FIN))[t];
        s0 += wa * ua.x + wb * ub.x;
        s1 += wa * ua.y + wb * ub.y;
        s2 += wa * ua.z + wb * ub.z;
        s3 += wa * ua.w + wb * ub.w;
    }
    if (j < end) {
        int sa = srcs[j];
        float wa = norms[j];
        float4 ua = ((const float4*)(x + (size_t)sa * FIN))[t];
        s0 += wa * ua.x; s1 += wa * ua.y; s2 += wa * ua.z; s3 += wa * ua.w;
    }
    ushort4 hv, lv;
    split_bf(s0, hv.x, lv.x); split_bf(s1, hv.y, lv.y);
    split_bf(s2, hv.z, lv.z); split_bf(s3, hv.w, lv.w);
    ((ushort4*)(axh + (size_t)i * FIN))[t] = hv;
    ((ushort4*)(axl + (size_t)i * FIN))[t] = lv;
}

// ---------------- MFMA split-bf16 GEMM (128^2, single-buffer 2-barrier + XCD swizzle) ----------------
// PROVEN structure (R3/R4: 147 us, MfmaUtil ~39%) + PROVEN XCD swizzle (R6: FETCH 348->95 MB).
// 32 KiB LDS -> 2-3 blocks/CU; implicit wave-level overlap hides staging (m114).
// C[M][N] = A[M][K] @ B[K][N]; A as hi/lo planes (switch A0->A1 at ksw), B transposed [N][K] hi/lo.
// mode 1: relu(acc+bias) -> split-store Chh/Chl. mode 0: acc+bias -> f32 Cf.
__global__ __launch_bounds__(256)
void gemm_mfma(const ush* __restrict__ A0h, const ush* __restrict__ A0l,
               const ush* __restrict__ A1h, const ush* __restrict__ A1l,
               int ksw, int KA,
               const ush* __restrict__ BTh, const ush* __restrict__ BTl,
               const float* __restrict__ bias,
               float* __restrict__ Cf, ush* __restrict__ Chh, ush* __restrict__ Chl,
               int M, int N, int K, int mode) {
    __shared__ ush Ah[128 * 32], Al[128 * 32], Bh[128 * 32], Bl[128 * 32];

    // bijective XCD swizzle (m204): each XCD owns a contiguous wg chunk -> A-panel L2 reuse
    int nwg = gridDim.x * gridDim.y;
    int orig = blockIdx.y * gridDim.x + blockIdx.x;
    int xcd = orig & 7, slot = orig >> 3;
    int q = nwg >> 3, r = nwg & 7;
    int wg = (xcd < r ? xcd * (q + 1) : r * (q + 1) + (xcd - r) * q) + slot;
    int bn = (wg % gridDim.x) * 128;
    int bm = (wg / gridDim.x) * 128;

    int t = threadIdx.x;
    int l = t & 63, w = t >> 6;
    int wr = w >> 1, wc = w & 1;

    // staging: lane covers 16B = 8 bf16; tile row = 32 bf16 = 64B; op covers 64 rows
    int sr = t >> 2;
    int sg8 = (t & 3) * 8;
    size_t a_off0 = (size_t)(bm + sr) * KA + sg8;
    size_t a_off1 = (size_t)(bm + 64 + sr) * KA + sg8;
    size_t b_off0 = (size_t)(bn + sr) * K + sg8;
    size_t b_off1 = (size_t)(bn + 64 + sr) * K + sg8;
    int lo0 = t * 16, lo1 = t * 16 + 4096;

    // ds_read frag base (bytes): row*64 + k-slot*16
    int abase = (wr * 64 + (l & 15)) * 64 + ((l >> 4) << 4);
    int bbase = (wc * 64 + (l & 15)) * 64 + ((l >> 4) << 4);

    f32x4 acc[4][4];
#pragma unroll
    for (int i = 0; i < 4; ++i)
#pragma unroll
        for (int j = 0; j < 4; ++j) acc[i][j] = (f32x4){0.f, 0.f, 0.f, 0.f};

    for (int kt = 0; kt < K; kt += 32) {
        const ush* Asrch; const ush* Asrcl; int kk;
        if (kt < ksw) { Asrch = A0h; Asrcl = A0l; kk = kt; }
        else          { Asrch = A1h; Asrcl = A1l; kk = kt - ksw; }

        gl16(Asrch + a_off0 + kk, (char*)Ah + lo0);
        gl16(Asrch + a_off1 + kk, (char*)Ah + lo1);
        gl16(Asrcl + a_off0 + kk, (char*)Al + lo0);
        gl16(Asrcl + a_off1 + kk, (char*)Al + lo1);
        gl16(BTh + b_off0 + kt, (char*)Bh + lo0);
        gl16(BTh + b_off1 + kt, (char*)Bh + lo1);
        gl16(BTl + b_off0 + kt, (char*)Bl + lo0);
        gl16(BTl + b_off1 + kt, (char*)Bl + lo1);
        __syncthreads();   // drains vmcnt; inter-block overlap hides it (2-3 blocks/CU)

        bf16x8 ah[4], al[4], bh[4], bl[4];
#pragma unroll
        for (int f = 0; f < 4; ++f) {
            ah[f] = *(const bf16x8*)((const char*)Ah + abase + f * 1024);
            al[f] = *(const bf16x8*)((const char*)Al + abase + f * 1024);
            bh[f] = *(const bf16x8*)((const char*)Bh + bbase + f * 1024);
            bl[f] = *(const bf16x8*)((const char*)Bl + bbase + f * 1024);
        }
        // 3-pass split-bf16: hi*hi + hi*lo + lo*hi
#pragma unroll
        for (int fm = 0; fm < 4; ++fm)
#pragma unroll
            for (int fn = 0; fn < 4; ++fn)
                acc[fm][fn] = __builtin_amdgcn_mfma_f32_16x16x32_bf16(ah[fm], bh[fn], acc[fm][fn], 0, 0, 0);
#pragma unroll
        for (int fm = 0; fm < 4; ++fm)
#pragma unroll
            for (int fn = 0; fn < 4; ++fn)
                acc[fm][fn] = __builtin_amdgcn_mfma_f32_16x16x32_bf16(ah[fm], bl[fn], acc[fm][fn], 0, 0, 0);
#pragma unroll
        for (int fm = 0; fm < 4; ++fm)
#pragma unroll
            for (int fn = 0; fn < 4; ++fn)
                acc[fm][fn] = __builtin_amdgcn_mfma_f32_16x16x32_bf16(al[fm], bh[fn], acc[fm][fn], 0, 0, 0);
        __syncthreads();   // protect LDS before next stage
    }

    // epilogue: C/D layout (verified): col = lane&15, row = (lane>>4)*4 + reg
    int ccol = bn + wc * 64 + (l & 15);
    float bb[4];
#pragma unroll
    for (int fn = 0; fn < 4; ++fn) bb[fn] = bias ? bias[ccol + fn * 16] : 0.0f;

    if (mode) {
#pragma unroll
        for (int fm = 0; fm < 4; ++fm)
#pragma unroll
            for (int j = 0; j < 4; ++j) {
                int row = bm + wr * 64 + fm * 16 + ((l >> 4) << 2) + j;
                if (row < M) {
#pragma unroll
                    for (int fn = 0; fn < 4; ++fn) {
                        float v = fmaxf(acc[fm][fn][j] + bb[fn], 0.0f);
                        ush hi, lo; split_bf(v, hi, lo);
                        size_t off = (size_t)row * N + ccol + fn * 16;
                        Chh[off] = hi;
                        Chl[off] = lo;
                    }
                }
            }
    } else {
#pragma unroll
        for (int fm = 0; fm < 4; ++fm)
#pragma unroll
            for (int j = 0; j < 4; ++j) {
                int row = bm + wr * 64 + fm * 16 + ((l >> 4) << 2) + j;
                if (row < M) {
#pragma unroll
                    for (int fn = 0; fn < 4; ++fn)
                        Cf[(size_t)row * N + ccol + fn * 16] = acc[fm][fn][j] + bb[fn];
                }
            }
    }
}

// ---------------- layer-2 aggregation + residual -> out ----------------
// z2[NN][256]: cols 0..127 = h@w2 (aggregate), cols 128..255 = h@rw2+b2+rb2 (residual)
__global__ __launch_bounds__(256)
void agg2_kernel(const float* __restrict__ z2, const float* __restrict__ dis,
                 const int* __restrict__ rowptr, const int* __restrict__ srcs,
                 const float* __restrict__ norms, float* __restrict__ out) {
    int wave = threadIdx.x >> 6;
    int lane = threadIdx.x & 63;
    int i = blockIdx.x * 4 + wave;
    float d = dis[i];
    float d2 = d * d;
    float2 v = ((const float2*)(z2 + (size_t)i * 256))[lane];
    float ax = d2 * v.x, ay = d2 * v.y;
    int beg = rowptr[i], end = rowptr[i + 1];
    int j = beg;
    for (; j + 2 <= end; j += 2) {
        int sa = srcs[j], sb = srcs[j + 1];
        float wa = norms[j], wb = norms[j + 1];
        float2 ua = ((const float2*)(z2 + (size_t)sa * 256))[lane];
        float2 ub = ((const float2*)(z2 + (size_t)sb * 256))[lane];
        ax += wa * ua.x + wb * ub.x;
        ay += wa * ua.y + wb * ub.y;
    }
    if (j < end) {
        int sa = srcs[j];
        float wa = norms[j];
        float2 ua = ((const float2*)(z2 + (size_t)sa * 256))[lane];
        ax += wa * ua.x; ay += wa * ua.y;
    }
    float2 rr = ((const float2*)(z2 + (size_t)i * 256 + 128))[lane];
    float2 o; o.x = ax + rr.x; o.y = ay + rr.y;
    ((float2*)(out + (size_t)i * OUTF))[lane] = o;
}

// ---------------- launch ----------------
extern "C" void kernel_launch(void* const* d_in, const int* in_sizes, int n_in,
                              void* d_out, int out_size, void* d_ws, size_t ws_size,
                              hipStream_t stream) {
    const float* x   = (const float*)d_in[0];
    const float* w1  = (const float*)d_in[1];
    const float* b1  = (const float*)d_in[2];
    const float* w2  = (const float*)d_in[3];
    const float* b2  = (const float*)d_in[4];
    const float* rw1 = (const float*)d_in[5];
    const float* rb1 = (const float*)d_in[6];
    const float* rw2 = (const float*)d_in[7];
    const float* rb2 = (const float*)d_in[8];
    const float* ew  = (const float*)d_in[9];
    const int*   ei  = (const int*)d_in[10];
    float* out = (float*)d_out;

    // -------- workspace layout (bytes) --------
    char* p = (char*)d_ws;
    ush* xh  = (ush*)p; p += (size_t)MPAD * FIN * 2;
    ush* xl  = (ush*)p; p += (size_t)MPAD * FIN * 2;
    ush* axh = (ush*)p; p += (size_t)MPAD * FIN * 2;
    ush* axl = (ush*)p; p += (size_t)MPAD * FIN * 2;
    ush* hh  = (ush*)p; p += (size_t)MPAD * HID * 2;
    ush* hl  = (ush*)p; p += (size_t)MPAD * HID * 2;
    ush* w1cth = (ush*)p; p += (size_t)HID * HID * 2;   // [1024 n][1024 k] = [w1;rw1]^T hi
    ush* w1ctl = (ush*)p; p += (size_t)HID * HID * 2;
    ush* w2cth = (ush*)p; p += (size_t)256 * HID * 2;   // [256 n][1024 k]: 0-127=w2^T, 128-255=rw2^T
    ush* w2ctl = (ush*)p; p += (size_t)256 * HID * 2;
    float* deg    = (float*)p; p += NN * 4;
    float* dis    = (float*)p; p += NN * 4;
    float* norms  = (float*)p; p += EE * 4;
    float* bias1s = (float*)p; p += HID * 4;
    float* bias2c = (float*)p; p += 256 * 4;
    int* rowptr = (int*)p; p += (NN + 1) * 4;
    int* cursor = (int*)p; p += NN * 4;
    int* cnt    = (int*)p; p += NN * 4;
    int* srcs   = (int*)p; p += EE * 4;
    float* z2 = (float*)xh;   // NN*256 f32 = 20.48 MB <= 20.7 MB plane (dead after layer-1)

    // 1. graph preprocessing (init+bias merged; dis folded into scan)
    init_kernel<<<(NN + 255) / 256, 256, 0, stream>>>(deg, cnt, NN, b1, rb1, b2, rb2, bias1s, bias2c);
    deg_count_kernel<<<(EE + 255) / 256, 256, 0, stream>>>(ei, ew, deg, cnt, EE);
    scan_kernel<<<1, SCAN_THREADS, 0, stream>>>(cnt, rowptr, cursor, NN, EE, deg, dis);
    scatter_kernel<<<(EE + 255) / 256, 256, 0, stream>>>(ei, ew, dis, cursor, srcs, norms, EE);

    // 2. weight conversions
    { dim3 g(HID / 32, FIN / 32); tsplit_kernel<<<g, 256, 0, stream>>>(w1,  FIN, HID, w1cth, w1ctl, HID, 0);   }
    { dim3 g(HID / 32, FIN / 32); tsplit_kernel<<<g, 256, 0, stream>>>(rw1, FIN, HID, w1cth, w1ctl, HID, FIN); }
    { dim3 g(OUTF / 32, HID / 32); tsplit_kernel<<<g, 256, 0, stream>>>(w2,  HID, OUTF, w2cth, w2ctl, HID, 0); }
    { dim3 g(OUTF / 32, HID / 32); tsplit_kernel<<<g, 256, 0, stream>>>(rw2, HID, OUTF,
                                        w2cth + (size_t)128 * HID, w2ctl + (size_t)128 * HID, HID, 0); }

    // 3. pre-aggregate x -> ax planes (+ fused split of x)
    aggx_kernel<<<NN, 128, 0, stream>>>(x, xh, xl, axh, axl, dis, rowptr, srcs, norms);

    // 4. fused layer-1: h = relu([ax|x] @ [w1;rw1] + b1+rb1), split-stored as hh/hl
    {
        dim3 grid(HID / 128, MPAD / 128);   // 8 x 158, bn fastest
        gemm_mfma<<<grid, 256, 0, stream>>>(axh, axl, xh, xl, FIN, FIN,
                                            w1cth, w1ctl, bias1s,
                                            nullptr, hh, hl,
                                            NN, HID, HID, 1);
    }
    // 5. layer-2 combined GEMM: z2 = h @ [w2|rw2] + [0|b2+rb2]   (N=256)
    {
        dim3 grid(256 / 128, MPAD / 128);   // 2 x 158
        gemm_mfma<<<grid, 256, 0, stream>>>(hh, hl, hh, hl, HID, HID,
                                            w2cth, w2ctl, bias2c,
                                            z2, nullptr, nullptr,
                                            NN, 256, HID, 0);
    }
    // 6. layer-2 aggregation + residual -> out
    agg2_kernel<<<NN / 4, 256, 0, stream>>>(z2, dis, rowptr, srcs, norms, out);
}